// Round 1
// baseline (5176.571 us; speedup 1.0000x reference)
//
#include <hip/hip_runtime.h>
#include <cstddef>

#define T_LEN 4096
#define EMB 768
#define NH 12
#define HD 64
#define WIN 512

// ---------------- GEMM f32: C[M,N] = A[M,K] @ B[K,N], row-major.
// 64x64 tile, 256 threads, 4x4 micro-tile, K-tile 16. Dims: M%64==0, N%64==0, K%16==0.
__global__ __launch_bounds__(256) void gemm_f32_64x64(const float* __restrict__ A,
                                                      const float* __restrict__ B,
                                                      float* __restrict__ C,
                                                      int M, int N, int K) {
    __shared__ float As[16][68];   // As[k][m], padded row (68*4=272B, 16B-aligned rows)
    __shared__ float Bs[16][68];   // Bs[k][n]
    const int tid = threadIdx.x;
    const int bm = blockIdx.y * 64;
    const int bn = blockIdx.x * 64;
    const int tm = (tid >> 4) << 2;   // 0..60
    const int tn = (tid & 15) << 2;   // 0..60

    const int lm  = tid >> 2;          // A tile row 0..63
    const int lk  = (tid & 3) << 2;    // A k offset {0,4,8,12}
    const int bkr = tid >> 4;          // B k row 0..15
    const int bnc = (tid & 15) << 2;   // B col offset

    float acc[4][4] = {};

    for (int k0 = 0; k0 < K; k0 += 16) {
        float4 a4 = *(const float4*)&A[(size_t)(bm + lm) * K + k0 + lk];
        As[lk + 0][lm] = a4.x;
        As[lk + 1][lm] = a4.y;
        As[lk + 2][lm] = a4.z;
        As[lk + 3][lm] = a4.w;
        *(float4*)&Bs[bkr][bnc] = *(const float4*)&B[(size_t)(k0 + bkr) * N + bn + bnc];
        __syncthreads();
#pragma unroll
        for (int k = 0; k < 16; ++k) {
            float4 av = *(float4*)&As[k][tm];
            float4 bv = *(float4*)&Bs[k][tn];
            acc[0][0] += av.x * bv.x; acc[0][1] += av.x * bv.y; acc[0][2] += av.x * bv.z; acc[0][3] += av.x * bv.w;
            acc[1][0] += av.y * bv.x; acc[1][1] += av.y * bv.y; acc[1][2] += av.y * bv.z; acc[1][3] += av.y * bv.w;
            acc[2][0] += av.z * bv.x; acc[2][1] += av.z * bv.y; acc[2][2] += av.z * bv.z; acc[2][3] += av.z * bv.w;
            acc[3][0] += av.w * bv.x; acc[3][1] += av.w * bv.y; acc[3][2] += av.w * bv.z; acc[3][3] += av.w * bv.w;
        }
        __syncthreads();
    }
#pragma unroll
    for (int i = 0; i < 4; ++i) {
        float4 cv = make_float4(acc[i][0], acc[i][1], acc[i][2], acc[i][3]);
        *(float4*)&C[(size_t)(bm + tm + i) * N + bn + tn] = cv;
    }
}

// ---------------- discoverability bias: d[h][t] = K_h[t]·u_h − mean_t(K_h·u_h)
__global__ __launch_bounds__(256) void dbias_kernel(const float* __restrict__ K,
                                                    const float* __restrict__ u,
                                                    float* __restrict__ d_bias) {
    const int h = blockIdx.x;
    const int tid = threadIdx.x;
    __shared__ __align__(16) float us[HD];
    __shared__ float dr[T_LEN];
    __shared__ float red[256];
    if (tid < HD) us[tid] = u[h * HD + tid];
    __syncthreads();
    const float4* u4 = (const float4*)us;
    float lsum = 0.f;
    for (int t = tid; t < T_LEN; t += 256) {
        const float4* Kp = (const float4*)&K[(size_t)t * EMB + h * HD];
        float acc = 0.f;
#pragma unroll
        for (int i = 0; i < HD / 4; ++i) {
            float4 k4 = Kp[i];
            float4 uu = u4[i];
            acc += k4.x * uu.x + k4.y * uu.y + k4.z * uu.z + k4.w * uu.w;
        }
        dr[t] = acc;
        lsum += acc;
    }
    red[tid] = lsum;
    __syncthreads();
    for (int off = 128; off > 0; off >>= 1) {
        if (tid < off) red[tid] += red[tid + off];
        __syncthreads();
    }
    const float mean = red[0] * (1.0f / (float)T_LEN);
    __syncthreads();
    for (int t = tid; t < T_LEN; t += 256) {
        d_bias[h * T_LEN + t] = dr[t] - mean;
    }
}

// ---------------- banded gated attention, one block per (t, h)
__global__ __launch_bounds__(256) void attn_kernel(const float* __restrict__ Q,
                                                   const float* __restrict__ K,
                                                   const float* __restrict__ V,
                                                   const float* __restrict__ d_bias,
                                                   const float* __restrict__ gates,
                                                   float* __restrict__ attn_out,
                                                   float* __restrict__ ctx) {
    const int t = blockIdx.x;
    const int h = blockIdx.y;
    const int tid = threadIdx.x;
    const int s_lo = (t - WIN > 0) ? (t - WIN) : 0;
    const int n_s = t - s_lo + 1;   // <= 513

    __shared__ __align__(16) float qt[HD];
    __shared__ __align__(16) float kt[HD];
    __shared__ float sl[WIN + 1];
    __shared__ float red[256];
    __shared__ float cpart[4][HD];

    // per-head gate softmax (3 values, computed redundantly per thread)
    const float g0 = gates[h * 3 + 0];
    const float g1 = gates[h * 3 + 1];
    const float g2 = gates[h * 3 + 2];
    const float gm = fmaxf(g0, fmaxf(g1, g2));
    const float e0 = expf(g0 - gm), e1 = expf(g1 - gm), e2 = expf(g2 - gm);
    const float ginv = 1.0f / (e0 + e1 + e2);
    const float w_std = e0 * ginv, w_rec = e1 * ginv, w_disc = e2 * ginv;

    if (tid < HD) qt[tid] = Q[(size_t)t * EMB + h * HD + tid];
    else if (tid < 2 * HD) kt[tid - HD] = K[(size_t)t * EMB + h * HD + (tid - HD)];
    __syncthreads();

    const float scale = 0.125f;   // 1/sqrt(64)
    const float4* qt4 = (const float4*)qt;
    const float4* kt4 = (const float4*)kt;

    float local_max = -1e30f;
    for (int j = tid; j < n_s; j += 256) {
        const int s = s_lo + j;
        const float4* Ks4 = (const float4*)&K[(size_t)s * EMB + h * HD];
        const float4* Qs4 = (const float4*)&Q[(size_t)s * EMB + h * HD];
        float acc1 = 0.f, acc2 = 0.f;
#pragma unroll
        for (int i = 0; i < HD / 4; ++i) {
            float4 kk = Ks4[i];
            float4 qq = Qs4[i];
            float4 qv = qt4[i];
            float4 kv = kt4[i];
            acc1 += qv.x * kk.x + qv.y * kk.y + qv.z * kk.z + qv.w * kk.w;
            acc2 += qq.x * kv.x + qq.y * kv.y + qq.z * kv.z + qq.w * kv.w;
        }
        const float logit = w_std * acc1 * scale + w_rec * acc2 * scale
                          + w_disc * d_bias[h * T_LEN + s];
        sl[j] = logit;
        local_max = fmaxf(local_max, logit);
    }
    red[tid] = local_max;
    __syncthreads();
    for (int off = 128; off > 0; off >>= 1) {
        if (tid < off) red[tid] = fmaxf(red[tid], red[tid + off]);
        __syncthreads();
    }
    const float row_max = red[0];
    __syncthreads();

    float local_sum = 0.f;
    for (int j = tid; j < n_s; j += 256) {
        const float p = expf(sl[j] - row_max);
        sl[j] = p;
        local_sum += p;
    }
    red[tid] = local_sum;
    __syncthreads();
    for (int off = 128; off > 0; off >>= 1) {
        if (tid < off) red[tid] += red[tid + off];
        __syncthreads();
    }
    const float inv_den = 1.0f / red[0];
    __syncthreads();

    for (int j = tid; j < n_s; j += 256) sl[j] *= inv_den;
    __syncthreads();

    // write full attn row (zeros outside the band)
    float* arow = attn_out + ((size_t)(h * T_LEN + t)) * T_LEN;
    for (int i = tid; i < T_LEN; i += 256) {
        float v = 0.f;
        if (i >= s_lo && i <= t) v = sl[i - s_lo];
        arow[i] = v;
    }

    // ctx[t, h*64+lane] = sum_s p[s] * V[s, h*64+lane]; 4 waves split s
    const int wv = tid >> 6;
    const int lane = tid & 63;
    float acc = 0.f;
    for (int j = wv; j < n_s; j += 4) {
        acc += sl[j] * V[(size_t)(s_lo + j) * EMB + h * HD + lane];
    }
    cpart[wv][lane] = acc;
    __syncthreads();
    if (tid < HD) {
        const float c = cpart[0][tid] + cpart[1][tid] + cpart[2][tid] + cpart[3][tid];
        ctx[(size_t)t * EMB + h * HD + tid] = c;
    }
}

extern "C" void kernel_launch(void* const* d_in, const int* in_sizes, int n_in,
                              void* d_out, int out_size, void* d_ws, size_t ws_size,
                              hipStream_t stream) {
    const float* x     = (const float*)d_in[0];
    const float* Wq    = (const float*)d_in[1];
    const float* Wk    = (const float*)d_in[2];
    const float* Wv    = (const float*)d_in[3];
    const float* Wo    = (const float*)d_in[4];
    const float* gates = (const float*)d_in[5];
    const float* u     = (const float*)d_in[6];

    float* out  = (float*)d_out;                       // [T, E]
    float* attn = out + (size_t)T_LEN * EMB;           // [H, T, T]

    float* ws = (float*)d_ws;
    float* Qb = ws;                                    // [T, E]
    float* Kb = Qb + (size_t)T_LEN * EMB;
    float* Vb = Kb + (size_t)T_LEN * EMB;
    float* Cb = Vb + (size_t)T_LEN * EMB;              // ctx [T, E]
    float* Db = Cb + (size_t)T_LEN * EMB;              // d bias [H, T]

    dim3 gg(EMB / 64, T_LEN / 64);
    gemm_f32_64x64<<<gg, 256, 0, stream>>>(x, Wq, Qb, T_LEN, EMB, EMB);
    gemm_f32_64x64<<<gg, 256, 0, stream>>>(x, Wk, Kb, T_LEN, EMB, EMB);
    gemm_f32_64x64<<<gg, 256, 0, stream>>>(x, Wv, Vb, T_LEN, EMB, EMB);
    dbias_kernel<<<NH, 256, 0, stream>>>(Kb, u, Db);
    attn_kernel<<<dim3(T_LEN, NH), 256, 0, stream>>>(Qb, Kb, Vb, Db, gates, attn, Cb);
    gemm_f32_64x64<<<gg, 256, 0, stream>>>(Cb, Wo, out, T_LEN, EMB, EMB);
}

// Round 5
// 5153.123 us; speedup vs baseline: 1.0046x; 1.0046x over previous
//
#include <hip/hip_runtime.h>
#include <cstddef>

#define T_LEN 4096
#define EMB 768
#define NH 12
#define HD 64
#define WIN 512

// ---------------- GEMM f32: C[M,N] = A[M,K] @ B[K,N], row-major.
__global__ __launch_bounds__(256) void gemm_f32_64x64(const float* __restrict__ A,
                                                      const float* __restrict__ B,
                                                      float* __restrict__ C,
                                                      int M, int N, int K) {
    __shared__ float As[16][68];
    __shared__ float Bs[16][68];
    const int tid = threadIdx.x;
    const int bm = blockIdx.y * 64;
    const int bn = blockIdx.x * 64;
    const int tm = (tid >> 4) << 2;
    const int tn = (tid & 15) << 2;

    const int lm  = tid >> 2;
    const int lk  = (tid & 3) << 2;
    const int bkr = tid >> 4;
    const int bnc = (tid & 15) << 2;

    float acc[4][4] = {};

    for (int k0 = 0; k0 < K; k0 += 16) {
        float4 a4 = *(const float4*)&A[(size_t)(bm + lm) * K + k0 + lk];
        As[lk + 0][lm] = a4.x;
        As[lk + 1][lm] = a4.y;
        As[lk + 2][lm] = a4.z;
        As[lk + 3][lm] = a4.w;
        *(float4*)&Bs[bkr][bnc] = *(const float4*)&B[(size_t)(k0 + bkr) * N + bn + bnc];
        __syncthreads();
#pragma unroll
        for (int k = 0; k < 16; ++k) {
            float4 av = *(float4*)&As[k][tm];
            float4 bv = *(float4*)&Bs[k][tn];
            acc[0][0] += av.x * bv.x; acc[0][1] += av.x * bv.y; acc[0][2] += av.x * bv.z; acc[0][3] += av.x * bv.w;
            acc[1][0] += av.y * bv.x; acc[1][1] += av.y * bv.y; acc[1][2] += av.y * bv.z; acc[1][3] += av.y * bv.w;
            acc[2][0] += av.z * bv.x; acc[2][1] += av.z * bv.y; acc[2][2] += av.z * bv.z; acc[2][3] += av.z * bv.w;
            acc[3][0] += av.w * bv.x; acc[3][1] += av.w * bv.y; acc[3][2] += av.w * bv.z; acc[3][3] += av.w * bv.w;
        }
        __syncthreads();
    }
#pragma unroll
    for (int i = 0; i < 4; ++i) {
        float4 cv = make_float4(acc[i][0], acc[i][1], acc[i][2], acc[i][3]);
        *(float4*)&C[(size_t)(bm + tm + i) * N + bn + tn] = cv;
    }
}

// ---------------- discoverability bias: d[h][t] = K_h[t]·u_h − mean
__global__ __launch_bounds__(256) void dbias_kernel(const float* __restrict__ K,
                                                    const float* __restrict__ u,
                                                    float* __restrict__ d_bias) {
    const int h = blockIdx.x;
    const int tid = threadIdx.x;
    __shared__ __align__(16) float us[HD];
    __shared__ float dr[T_LEN];
    __shared__ float red[256];
    if (tid < HD) us[tid] = u[h * HD + tid];
    __syncthreads();
    const float4* u4 = (const float4*)us;
    float lsum = 0.f;
    for (int t = tid; t < T_LEN; t += 256) {
        const float4* Kp = (const float4*)&K[(size_t)t * EMB + h * HD];
        float acc = 0.f;
#pragma unroll
        for (int i = 0; i < HD / 4; ++i) {
            float4 k4 = Kp[i];
            float4 uu = u4[i];
            acc += k4.x * uu.x + k4.y * uu.y + k4.z * uu.z + k4.w * uu.w;
        }
        dr[t] = acc;
        lsum += acc;
    }
    red[tid] = lsum;
    __syncthreads();
    for (int off = 128; off > 0; off >>= 1) {
        if (tid < off) red[tid] += red[tid + off];
        __syncthreads();
    }
    const float mean = red[0] * (1.0f / (float)T_LEN);
    __syncthreads();
    for (int t = tid; t < T_LEN; t += 256) {
        d_bias[h * T_LEN + t] = dr[t] - mean;
    }
}

// ---------------- banded gated attention, one block per (t, h) — R0-proven structure
// with shuffle reductions, float4 row writes, fused normalization.
__global__ __launch_bounds__(256) void attn_kernel(const float* __restrict__ Q,
                                                   const float* __restrict__ K,
                                                   const float* __restrict__ V,
                                                   const float* __restrict__ d_bias,
                                                   const float* __restrict__ gates,
                                                   float* __restrict__ attn_out,
                                                   float* __restrict__ ctx) {
    const int t = blockIdx.x;
    const int h = blockIdx.y;
    const int tid = threadIdx.x;
    const int w = tid >> 6;
    const int lane = tid & 63;
    const int s_lo = (t - WIN > 0) ? (t - WIN) : 0;
    const int n_s = t - s_lo + 1;   // <= 513

    __shared__ __align__(16) float qt[HD];
    __shared__ __align__(16) float kt[HD];
    __shared__ float sl[WIN + 4];   // up to 513 used
    __shared__ float wmax[4];
    __shared__ float wsum[4];
    __shared__ float cpart[4][HD];

    // per-head gate softmax (3 values, computed redundantly per thread)
    const float g0 = gates[h * 3 + 0];
    const float g1 = gates[h * 3 + 1];
    const float g2 = gates[h * 3 + 2];
    const float gm = fmaxf(g0, fmaxf(g1, g2));
    const float e0 = __expf(g0 - gm), e1 = __expf(g1 - gm), e2 = __expf(g2 - gm);
    const float ginv = 1.0f / (e0 + e1 + e2);
    const float w_std = e0 * ginv, w_rec = e1 * ginv, w_disc = e2 * ginv;

    if (tid < HD) qt[tid] = Q[(size_t)t * EMB + h * HD + tid];
    else if (tid < 2 * HD) kt[tid - HD] = K[(size_t)t * EMB + h * HD + (tid - HD)];
    __syncthreads();

    const float scale = 0.125f;   // 1/sqrt(64)
    const float4* qt4 = (const float4*)qt;
    const float4* kt4 = (const float4*)kt;

    float local_max = -1e30f;
    for (int j = tid; j < n_s; j += 256) {
        const int s = s_lo + j;
        const float4* Ks4 = (const float4*)&K[(size_t)s * EMB + h * HD];
        const float4* Qs4 = (const float4*)&Q[(size_t)s * EMB + h * HD];
        float acc1 = 0.f, acc2 = 0.f;
#pragma unroll
        for (int i = 0; i < HD / 4; ++i) {
            float4 kk = Ks4[i];
            float4 qq = Qs4[i];
            float4 qv = qt4[i];
            float4 kv = kt4[i];
            acc1 += qv.x * kk.x + qv.y * kk.y + qv.z * kk.z + qv.w * kk.w;
            acc2 += qq.x * kv.x + qq.y * kv.y + qq.z * kv.z + qq.w * kv.w;
        }
        const float logit = w_std * acc1 * scale + w_rec * acc2 * scale
                          + w_disc * d_bias[h * T_LEN + s];
        sl[j] = logit;
        local_max = fmaxf(local_max, logit);
    }
    // wave-wide max, then cross-wave via 4-slot LDS
    float m = local_max;
#pragma unroll
    for (int off = 32; off > 0; off >>= 1) m = fmaxf(m, __shfl_xor(m, off));
    if (lane == 0) wmax[w] = m;
    __syncthreads();
    const float row_max = fmaxf(fmaxf(wmax[0], wmax[1]), fmaxf(wmax[2], wmax[3]));

    float local_sum = 0.f;
    for (int j = tid; j < n_s; j += 256) {
        const float p = __expf(sl[j] - row_max);
        sl[j] = p;
        local_sum += p;
    }
    float ssum = local_sum;
#pragma unroll
    for (int off = 32; off > 0; off >>= 1) ssum += __shfl_xor(ssum, off);
    if (lane == 0) wsum[w] = ssum;
    __syncthreads();   // also publishes all sl[j] = p
    const float inv_den = 1.0f / (wsum[0] + wsum[1] + wsum[2] + wsum[3]);

    // write full attn row (zeros outside band), float4, normalize on the fly
    float* arow = attn_out + ((size_t)(h * T_LEN + t)) * T_LEN;
    for (int i4 = tid * 4; i4 < T_LEN; i4 += 1024) {
        float4 v;
        const int i0 = i4;
        v.x = (i0 + 0 >= s_lo && i0 + 0 <= t) ? sl[i0 + 0 - s_lo] * inv_den : 0.f;
        v.y = (i0 + 1 >= s_lo && i0 + 1 <= t) ? sl[i0 + 1 - s_lo] * inv_den : 0.f;
        v.z = (i0 + 2 >= s_lo && i0 + 2 <= t) ? sl[i0 + 2 - s_lo] * inv_den : 0.f;
        v.w = (i0 + 3 >= s_lo && i0 + 3 <= t) ? sl[i0 + 3 - s_lo] * inv_den : 0.f;
        *(float4*)&arow[i4] = v;
    }

    // ctx[t, h*64+lane] = inv_den * sum_s p[s] * V[s, h*64+lane]; 4 waves split s
    float acc = 0.f;
    for (int j = w; j < n_s; j += 4) {
        acc += sl[j] * V[(size_t)(s_lo + j) * EMB + h * HD + lane];
    }
    cpart[w][lane] = acc;
    __syncthreads();
    if (tid < HD) {
        const float c = (cpart[0][tid] + cpart[1][tid] + cpart[2][tid] + cpart[3][tid]) * inv_den;
        ctx[(size_t)t * EMB + h * HD + tid] = c;
    }
}

extern "C" void kernel_launch(void* const* d_in, const int* in_sizes, int n_in,
                              void* d_out, int out_size, void* d_ws, size_t ws_size,
                              hipStream_t stream) {
    const float* x     = (const float*)d_in[0];
    const float* Wq    = (const float*)d_in[1];
    const float* Wk    = (const float*)d_in[2];
    const float* Wv    = (const float*)d_in[3];
    const float* Wo    = (const float*)d_in[4];
    const float* gates = (const float*)d_in[5];
    const float* u     = (const float*)d_in[6];

    float* out  = (float*)d_out;                       // [T, E]
    float* attn = out + (size_t)T_LEN * EMB;           // [H, T, T]

    float* ws = (float*)d_ws;
    float* Qb = ws;
    float* Kb = Qb + (size_t)T_LEN * EMB;
    float* Vb = Kb + (size_t)T_LEN * EMB;
    float* Cb = Vb + (size_t)T_LEN * EMB;
    float* Db = Cb + (size_t)T_LEN * EMB;              // d bias [H, T]

    dim3 gg(EMB / 64, T_LEN / 64);
    gemm_f32_64x64<<<gg, 256, 0, stream>>>(x, Wq, Qb, T_LEN, EMB, EMB);
    gemm_f32_64x64<<<gg, 256, 0, stream>>>(x, Wk, Kb, T_LEN, EMB, EMB);
    gemm_f32_64x64<<<gg, 256, 0, stream>>>(x, Wv, Vb, T_LEN, EMB, EMB);
    dbias_kernel<<<NH, 256, 0, stream>>>(Kb, u, Db);

    attn_kernel<<<dim3(T_LEN, NH), 256, 0, stream>>>(Qb, Kb, Vb, Db, gates, attn, Cb);

    gemm_f32_64x64<<<gg, 256, 0, stream>>>(Cb, Wo, out, T_LEN, EMB, EMB);
}